// Round 7
// baseline (596.118 us; speedup 1.0000x reference)
//
#include <hip/hip_runtime.h>
#include <hip/hip_bf16.h>

#define NN 100000
#define NE 1600000
#define NG 1000
#define SMAX 48

typedef unsigned short u16;
typedef unsigned int u32;
typedef u16 u16x8 __attribute__((ext_vector_type(8)));
typedef u32 u32x4 __attribute__((ext_vector_type(4)));
typedef float f32x4 __attribute__((ext_vector_type(4)));
typedef __attribute__((ext_vector_type(8))) short s16x8;
typedef __attribute__((ext_vector_type(4))) float facc4;

__device__ __forceinline__ float bf2f(u16 u) {
    union { u32 i; float f; } c; c.i = ((u32)u) << 16; return c.f;
}
__device__ __forceinline__ u16 f2bf(float f) {
    __hip_bfloat16 h = __float2bfloat16(f);
    union { __hip_bfloat16 h; u16 u; } c; c.h = h; return c.u;
}
__device__ __forceinline__ int ntload(const int* p) { return __builtin_nontemporal_load(p); }

// ---------------- dtype detector: flag=1 if x is bf16, 0 if f32 ----------------
__global__ __launch_bounds__(256) void detect_kernel(const u32* __restrict__ xr, int* __restrict__ flag) {
    __shared__ int cnt[256];
    int c = 0;
    for (int i = threadIdx.x; i < 4096; i += 256) {
        u32 e = (xr[i] >> 7) & 0xFFu;
        if (e >= 110u && e <= 135u) c++;
    }
    cnt[threadIdx.x] = c;
    __syncthreads();
    for (int o = 128; o > 0; o >>= 1) {
        if (threadIdx.x < o) cnt[threadIdx.x] += cnt[threadIdx.x + o];
        __syncthreads();
    }
    if (threadIdx.x == 0) flag[0] = (cnt[0] > 2048) ? 1 : 0;
}

// ---------------- MEGA prep: cvt_x | cvt_wt x4 | cvt_b x4 | hist(1/thr), by block range -------
// ranges: [0,6250) cvt_x ; [6250,6474) cvt_wt ; [6474,6476) cvt_b ; [6476,12726) hist
#define MEGA_NB 12726
__global__ __launch_bounds__(256) void mega_prep(
    const void* __restrict__ x, const int* __restrict__ flag, u16* __restrict__ xb,
    const void* __restrict__ Wemb, const void* __restrict__ W1, const void* __restrict__ W2,
    const void* __restrict__ W3, u16* __restrict__ wembT, u16* __restrict__ w1T,
    u16* __restrict__ w2T, u16* __restrict__ w3T,
    const void* __restrict__ bemb, const void* __restrict__ b1, const void* __restrict__ b2,
    const void* __restrict__ b3, float* __restrict__ bembF, float* __restrict__ b1F,
    float* __restrict__ b2F, float* __restrict__ b3F,
    const int* __restrict__ ei, int* __restrict__ counts)
{
    int b = blockIdx.x, tid = threadIdx.x;
    int fl = flag[0];
    if (b < 6250) {                       // ---- cvt_x (skip when already bf16)
        if (fl) return;
        int c = b * 256 + tid;
        f32x4 a = reinterpret_cast<const f32x4*>(x)[c * 2];
        f32x4 d = reinterpret_cast<const f32x4*>(x)[c * 2 + 1];
        u16x8 o;
        #pragma unroll
        for (int j = 0; j < 4; ++j) { o[j] = f2bf(a[j]); o[4 + j] = f2bf(d[j]); }
        reinterpret_cast<u16x8*>(xb)[c] = o;
    } else if (b < 6474) {                // ---- cvt_wt (transpose W[k][m] -> Wt[m][k])
        int o = (b - 6250) * 256 + tid;
        const void* src; u16* dst; int M; int ol;
        if (o < 16384)      { src = Wemb; dst = wembT; M = 128; ol = o; }
        else if (o < 32768) { src = W1;   dst = w1T;   M = 128; ol = o - 16384; }
        else if (o < 49152) { src = W2;   dst = w2T;   M = 128; ol = o - 32768; }
        else                { src = W3;   dst = w3T;   M = 64;  ol = o - 49152; }
        int n = ol >> 7, k = ol & 127;
        u16 v = fl ? reinterpret_cast<const u16*>(src)[k * M + n]
                   : f2bf(reinterpret_cast<const float*>(src)[k * M + n]);
        dst[ol] = v;
    } else if (b < 6476) {                // ---- cvt_b
        int i = (b - 6474) * 256 + tid;
        if (i >= 448) return;
        const void* src; float* dst; int il;
        if (i < 128)      { src = bemb; dst = bembF; il = i; }
        else if (i < 256) { src = b1;   dst = b1F;   il = i - 128; }
        else if (i < 384) { src = b2;   dst = b2F;   il = i - 256; }
        else              { src = b3;   dst = b3F;   il = i - 384; }
        dst[il] = fl ? bf2f(reinterpret_cast<const u16*>(src)[il])
                     : reinterpret_cast<const float*>(src)[il];
    } else {                              // ---- hist (1 edge / thread: max TLP)
        int e = (b - 6476) * 256 + tid;
        if (e < NE) atomicAdd(&counts[ei[NE + e]], 1);
    }
}

// ---------------- wfuse: WfT = w1T @ wembT (bf16), bfW = b_emb @ W1 (f32) ----------------
__global__ __launch_bounds__(256) void wfuse_kernel(const u16* __restrict__ w1T, const u16* __restrict__ wembT,
                                                    const float* __restrict__ bembF,
                                                    u16* __restrict__ WfT, float* __restrict__ bfW) {
    int b = blockIdx.x;
    if (b < 64) {
        int o = b * 256 + threadIdx.x;    // 0..16383
        int n = o >> 7, k = o & 127;
        float acc = 0.f;
        #pragma unroll 4
        for (int j = 0; j < 128; ++j)
            acc += bf2f(w1T[n * 128 + j]) * bf2f(wembT[j * 128 + k]);
        WfT[o] = f2bf(acc);
    } else {
        int n = threadIdx.x;
        if (n < 128) {
            float acc = 0.f;
            for (int j = 0; j < 128; ++j)
                acc += bembF[j] * bf2f(w1T[n * 128 + j]);
            bfW[n] = acc;
        }
    }
}

// ---------------- scan1 (+ dis, + cursor zero) ----------------
__global__ __launch_bounds__(256) void scan1_kernel(const int* __restrict__ counts, int* __restrict__ offs,
                                                    int* __restrict__ bsums, float* __restrict__ dis,
                                                    int* __restrict__ cursor) {
    __shared__ int sums[256];
    int tid = threadIdx.x;
    int base = blockIdx.x * 2048 + tid * 8;
    int local[8];
    int s = 0;
    #pragma unroll
    for (int i = 0; i < 8; ++i) {
        int v = 0;
        if (base + i < NN) {
            v = counts[base + i];
            dis[base + i] = rsqrtf((float)v + 1.0f);
            cursor[base + i] = 0;
        }
        local[i] = s; s += v;
    }
    sums[tid] = s;
    __syncthreads();
    for (int o = 1; o < 256; o <<= 1) {
        int v = (tid >= o) ? sums[tid - o] : 0;
        __syncthreads();
        sums[tid] += v;
        __syncthreads();
    }
    int excl = sums[tid] - s;
    #pragma unroll
    for (int i = 0; i < 8; ++i)
        if (base + i < NN) offs[base + i] = excl + local[i];
    if (tid == 255) bsums[blockIdx.x] = sums[255];
}

// ---------------- scan3 (folds block-sum prefix) ----------------
__global__ __launch_bounds__(256) void scan3_kernel(int* __restrict__ offs, const int* __restrict__ bsums) {
    __shared__ int addv;
    int i = blockIdx.x * 256 + threadIdx.x;
    int bucket = blockIdx.x >> 3;
    if (threadIdx.x == 0) {
        int s = 0;
        for (int k = 0; k < bucket; ++k) s += bsums[k];
        addv = s;
    }
    __syncthreads();
    if (i < NN) offs[i] += addv;
}

// ---------------- scatter: standalone, 1 edge/thread (proven 78 µs shape) ----------------
__global__ __launch_bounds__(256) void scatter_kernel(const int* __restrict__ ei, const int* __restrict__ offs,
                                                      int* __restrict__ cursor, int* __restrict__ srcs) {
    int e = blockIdx.x * 256 + threadIdx.x;
    if (e < NE) {
        int s = ei[e], d = ei[NE + e];
        int pos = offs[d] + atomicAdd(&cursor[d], 1);
        srcs[pos] = s;
    }
}

// ---------------- fused-embedding GEMM: hA = x @ WfT(+LDS) + bfW ----------------
__global__ __launch_bounds__(256) void gemm_emb(const u16* __restrict__ xb, const u16* __restrict__ xraw,
                                                const int* __restrict__ flag, const u16* __restrict__ WfT,
                                                const float* __restrict__ bfW, u16* __restrict__ Hout) {
    __shared__ u16 sW[128 * 136];
    int tid = threadIdx.x;
    const u16* A = flag[0] ? xraw : xb;
    for (int c = tid; c < 128 * 16; c += 256) {
        int n = c >> 4, kc = (c & 15) << 3;
        *reinterpret_cast<u16x8*>(sW + n * 136 + kc) = reinterpret_cast<const u16x8*>(WfT)[c];
    }
    __syncthreads();
    int wv = tid >> 6, lane = tid & 63;
    int m = lane & 15, quad = lane >> 4;
    int r0 = blockIdx.x * 64 + wv * 16;
    int ar = r0 + m; if (ar >= NN) ar = NN - 1;
    facc4 acc[8];
    #pragma unroll
    for (int t = 0; t < 8; ++t) acc[t] = (facc4){0.f, 0.f, 0.f, 0.f};
    const u16* arow = A + (size_t)ar * 128 + quad * 8;
    #pragma unroll
    for (int k0 = 0; k0 < 128; k0 += 32) {
        s16x8 a = *reinterpret_cast<const s16x8*>(arow + k0);
        #pragma unroll
        for (int t = 0; t < 8; ++t) {
            s16x8 bfr = *reinterpret_cast<const s16x8*>(sW + (t * 16 + m) * 136 + k0 + quad * 8);
            acc[t] = __builtin_amdgcn_mfma_f32_16x16x32_bf16(a, bfr, acc[t], 0, 0, 0);
        }
    }
    #pragma unroll
    for (int t = 0; t < 8; ++t) {
        int col = t * 16 + m;
        float bv = bfW[col];
        #pragma unroll
        for (int r = 0; r < 4; ++r) {
            int orow = r0 + quad * 4 + r;
            if (orow < NN)
                Hout[(size_t)orow * 128 + col] = f2bf(acc[t][r] + bv);
        }
    }
}

// ---------------- FUSED: agg(128-wide, +bias, relu) -> LDS -> MFMA gemm (x W[128,MOUT]) -------
template <int MOUT>
__global__ __launch_bounds__(256) void fused_agg_gemm(const u16* __restrict__ T, const int* __restrict__ offs,
                                                      const int* __restrict__ counts, const float* __restrict__ dis,
                                                      const int* __restrict__ srcs, const float* __restrict__ aggbias,
                                                      const u16* __restrict__ Wt, u16* __restrict__ Hout) {
    constexpr int LDW = 136;
    __shared__ u16 sW[MOUT * LDW];
    __shared__ u16 sA[64 * LDW];
    int tid = threadIdx.x;
    for (int c = tid; c < MOUT * 16; c += 256) {
        int n = c >> 4, kc = (c & 15) << 3;
        *reinterpret_cast<u16x8*>(sW + n * LDW + kc) = reinterpret_cast<const u16x8*>(Wt)[c];
    }

    int lane = tid & 15, grp = tid >> 4;
    const u32x4* T4 = reinterpret_cast<const u32x4*>(T);
    for (int i = 0; i < 4; ++i) {
        int nl = grp * 4 + i;
        int n = blockIdx.x * 64 + nl;
        bool valid = n < NN;
        int nc = valid ? n : NN - 1;
        float di = dis[nc];
        float sn = di * di;
        u32x4 ts = T4[(size_t)nc * 16 + lane];
        float acc[8];
        #pragma unroll
        for (int q = 0; q < 4; ++q) {
            acc[2 * q]     = bf2f((u16)(ts[q] & 0xffffu)) * sn + aggbias[lane * 8 + 2 * q];
            acc[2 * q + 1] = bf2f((u16)(ts[q] >> 16))     * sn + aggbias[lane * 8 + 2 * q + 1];
        }
        int st = offs[nc], cnt = valid ? counts[nc] : 0;
        int j = 0;
        for (; j + 8 <= cnt; j += 8) {              // 8-deep gather pipeline
            int e[8]; float w[8]; u32x4 g[8];
            #pragma unroll
            for (int u = 0; u < 8; ++u) e[u] = ntload(srcs + st + j + u);
            #pragma unroll
            for (int u = 0; u < 8; ++u) w[u] = dis[e[u]] * di;
            #pragma unroll
            for (int u = 0; u < 8; ++u) g[u] = T4[(size_t)e[u] * 16 + lane];
            #pragma unroll
            for (int u = 0; u < 8; ++u)
                #pragma unroll
                for (int q = 0; q < 4; ++q) {
                    acc[2 * q]     += bf2f((u16)(g[u][q] & 0xffffu)) * w[u];
                    acc[2 * q + 1] += bf2f((u16)(g[u][q] >> 16))     * w[u];
                }
        }
        for (; j + 4 <= cnt; j += 4) {
            int e[4]; float w[4]; u32x4 g[4];
            #pragma unroll
            for (int u = 0; u < 4; ++u) e[u] = ntload(srcs + st + j + u);
            #pragma unroll
            for (int u = 0; u < 4; ++u) w[u] = dis[e[u]] * di;
            #pragma unroll
            for (int u = 0; u < 4; ++u) g[u] = T4[(size_t)e[u] * 16 + lane];
            #pragma unroll
            for (int u = 0; u < 4; ++u)
                #pragma unroll
                for (int q = 0; q < 4; ++q) {
                    acc[2 * q]     += bf2f((u16)(g[u][q] & 0xffffu)) * w[u];
                    acc[2 * q + 1] += bf2f((u16)(g[u][q] >> 16))     * w[u];
                }
        }
        for (; j < cnt; ++j) {
            int e = ntload(srcs + st + j);
            float w = dis[e] * di;
            u32x4 g = T4[(size_t)e * 16 + lane];
            #pragma unroll
            for (int q = 0; q < 4; ++q) {
                acc[2 * q]     += bf2f((u16)(g[q] & 0xffffu)) * w;
                acc[2 * q + 1] += bf2f((u16)(g[q] >> 16))     * w;
            }
        }
        u16x8 pk;
        #pragma unroll
        for (int q = 0; q < 4; ++q) {
            pk[2 * q]     = f2bf(fmaxf(acc[2 * q], 0.0f));
            pk[2 * q + 1] = f2bf(fmaxf(acc[2 * q + 1], 0.0f));
        }
        *reinterpret_cast<u16x8*>(sA + nl * LDW + lane * 8) = pk;
    }
    __syncthreads();

    int wv = tid >> 6, l64 = tid & 63;
    int m = l64 & 15, quad = l64 >> 4;
    int r0 = blockIdx.x * 64 + wv * 16;
    constexpr int NT = MOUT / 16;
    facc4 gacc[NT];
    #pragma unroll
    for (int t = 0; t < NT; ++t) gacc[t] = (facc4){0.f, 0.f, 0.f, 0.f};
    #pragma unroll
    for (int k0 = 0; k0 < 128; k0 += 32) {
        s16x8 a = *reinterpret_cast<const s16x8*>(sA + (wv * 16 + m) * LDW + k0 + quad * 8);
        #pragma unroll
        for (int t = 0; t < NT; ++t) {
            s16x8 bfr = *reinterpret_cast<const s16x8*>(sW + (t * 16 + m) * LDW + k0 + quad * 8);
            gacc[t] = __builtin_amdgcn_mfma_f32_16x16x32_bf16(a, bfr, gacc[t], 0, 0, 0);
        }
    }
    #pragma unroll
    for (int t = 0; t < NT; ++t) {
        int col = t * 16 + m;
        #pragma unroll
        for (int r = 0; r < 4; ++r) {
            int orow = r0 + quad * 4 + r;
            if (orow < NN)
                Hout[(size_t)orow * MOUT + col] = f2bf(gacc[t][r]);
        }
    }
}

// ---------------- FUSED agg3 (+b3, no relu) + global add pool -> f32 outF ----------------
__global__ __launch_bounds__(256) void agg_pool_kernel(const u16* __restrict__ T, const int* __restrict__ offs,
                                                       const int* __restrict__ counts, const float* __restrict__ dis,
                                                       const int* __restrict__ srcs, const float* __restrict__ bias,
                                                       const int* __restrict__ batch, float* __restrict__ outF) {
    __shared__ float accG[SMAX * 64];
    __shared__ int sg0;
    int tid = threadIdx.x;
    for (int i = tid; i < SMAX * 64; i += 256) accG[i] = 0.0f;
    if (tid == 0) sg0 = batch[blockIdx.x * 32];
    __syncthreads();
    int g0 = sg0;
    int lane = tid & 7;
    int n = blockIdx.x * 32 + (tid >> 3);

    const u32x4* T4 = reinterpret_cast<const u32x4*>(T);
    float di = dis[n];
    float sn = di * di;
    u32x4 ts = T4[(size_t)n * 8 + lane];
    float acc[8];
    #pragma unroll
    for (int q = 0; q < 4; ++q) {
        acc[2 * q]     = bf2f((u16)(ts[q] & 0xffffu)) * sn + bias[lane * 8 + 2 * q];
        acc[2 * q + 1] = bf2f((u16)(ts[q] >> 16))     * sn + bias[lane * 8 + 2 * q + 1];
    }
    int st = offs[n], cnt = counts[n];
    int j = 0;
    for (; j + 8 <= cnt; j += 8) {
        int e[8]; float w[8]; u32x4 g[8];
        #pragma unroll
        for (int u = 0; u < 8; ++u) e[u] = ntload(srcs + st + j + u);
        #pragma unroll
        for (int u = 0; u < 8; ++u) w[u] = dis[e[u]] * di;
        #pragma unroll
        for (int u = 0; u < 8; ++u) g[u] = T4[(size_t)e[u] * 8 + lane];
        #pragma unroll
        for (int u = 0; u < 8; ++u)
            #pragma unroll
            for (int q = 0; q < 4; ++q) {
                acc[2 * q]     += bf2f((u16)(g[u][q] & 0xffffu)) * w[u];
                acc[2 * q + 1] += bf2f((u16)(g[u][q] >> 16))     * w[u];
            }
    }
    for (; j + 4 <= cnt; j += 4) {
        int e[4]; float w[4]; u32x4 g[4];
        #pragma unroll
        for (int u = 0; u < 4; ++u) e[u] = ntload(srcs + st + j + u);
        #pragma unroll
        for (int u = 0; u < 4; ++u) w[u] = dis[e[u]] * di;
        #pragma unroll
        for (int u = 0; u < 4; ++u) g[u] = T4[(size_t)e[u] * 8 + lane];
        #pragma unroll
        for (int u = 0; u < 4; ++u)
            #pragma unroll
            for (int q = 0; q < 4; ++q) {
                acc[2 * q]     += bf2f((u16)(g[u][q] & 0xffffu)) * w[u];
                acc[2 * q + 1] += bf2f((u16)(g[u][q] >> 16))     * w[u];
            }
    }
    for (; j < cnt; ++j) {
        int e = ntload(srcs + st + j);
        float w = dis[e] * di;
        u32x4 g = T4[(size_t)e * 8 + lane];
        #pragma unroll
        for (int q = 0; q < 4; ++q) {
            acc[2 * q]     += bf2f((u16)(g[q] & 0xffffu)) * w;
            acc[2 * q + 1] += bf2f((u16)(g[q] >> 16))     * w;
        }
    }

    int s = batch[n] - g0;
    if (s >= 0 && s < SMAX) {
        #pragma unroll
        for (int q = 0; q < 8; ++q)
            atomicAdd(&accG[s * 64 + lane * 8 + q], acc[q]);
    } else {
        #pragma unroll
        for (int q = 0; q < 8; ++q)
            atomicAdd(&outF[(size_t)(g0 + s) * 64 + lane * 8 + q], acc[q]);
    }
    __syncthreads();
    int gend = batch[blockIdx.x * 32 + 31];
    int span = gend - g0 + 1;
    if (span > SMAX) span = SMAX;
    for (int i = tid; i < span * 64; i += 256)
        atomicAdd(&outF[(size_t)g0 * 64 + i], accG[i]);
}

// ---------------- outF -> d_out (dtype branched) ----------------
__global__ __launch_bounds__(256) void out_cvt_kernel(const float* __restrict__ outF, void* __restrict__ out,
                                                      const int* __restrict__ flag) {
    int i = blockIdx.x * 256 + threadIdx.x;
    if (i < NG * 64) {
        float v = outF[i];
        if (flag[0]) reinterpret_cast<u16*>(out)[i] = f2bf(v);
        else         reinterpret_cast<float*>(out)[i] = v;
    }
}

extern "C" void kernel_launch(void* const* d_in, const int* in_sizes, int n_in,
                              void* d_out, int out_size, void* d_ws, size_t ws_size,
                              hipStream_t stream) {
    const void* x     = d_in[0];
    const int* ei     = (const int*)d_in[1];
    const int* batch  = (const int*)d_in[2];
    const void* W_emb = d_in[3];
    const void* b_emb = d_in[4];
    const void* W1    = d_in[5];
    const void* b1    = d_in[6];
    const void* W2    = d_in[7];
    const void* b2    = d_in[8];
    const void* W3    = d_in[9];
    const void* b3    = d_in[10];

    char* p = (char*)d_ws;
    auto alloc = [&](size_t bytes) { void* r = p; p += (bytes + 255) & ~(size_t)255; return r; };
    int*   flag   = (int*)alloc(256);
    int*   counts = (int*)alloc(NN * 4);
    int*   cursor = (int*)alloc(NN * 4);
    int*   offs   = (int*)alloc(NN * 4);
    float* dis    = (float*)alloc(NN * 4);
    int*   bsums  = (int*)alloc(256 * 4);
    int*   srcs   = (int*)alloc((size_t)NE * 4);
    u16*   wembT  = (u16*)alloc(128 * 128 * 2);
    u16*   w1T    = (u16*)alloc(128 * 128 * 2);
    u16*   w2T    = (u16*)alloc(128 * 128 * 2);
    u16*   w3T    = (u16*)alloc(64 * 128 * 2);
    u16*   WfT    = (u16*)alloc(128 * 128 * 2);
    float* bembF  = (float*)alloc(128 * 4);
    float* b1F    = (float*)alloc(128 * 4);
    float* b2F    = (float*)alloc(128 * 4);
    float* b3F    = (float*)alloc(64 * 4);
    float* bfW    = (float*)alloc(128 * 4);
    float* outF   = (float*)alloc((size_t)NG * 64 * 4);
    u16*   hA     = (u16*)alloc((size_t)(NN + 64) * 128 * 2);
    u16*   hB     = (u16*)alloc((size_t)(NN + 64) * 128 * 2);   // holds canonical bf16 x first

    hipMemsetAsync(counts, 0, NN * 4, stream);
    hipMemsetAsync(outF, 0, (size_t)NG * 64 * 4, stream);

    const int SB = (NN + 2047) / 2048;   // 49
    const int NB = (NN + 255) / 256;     // 391
    const int GB = (NN + 63) / 64;       // 1563
    const int EB = (NE + 255) / 256;     // 6250

    detect_kernel<<<1, 256, 0, stream>>>((const u32*)x, flag);
    mega_prep<<<MEGA_NB, 256, 0, stream>>>(x, flag, hB, W_emb, W1, W2, W3, wembT, w1T, w2T, w3T,
                                           b_emb, b1, b2, b3, bembF, b1F, b2F, b3F, ei, counts);
    // Wf = W_emb @ W1 (folds layer-1 transform into the embedding GEMM)
    wfuse_kernel<<<65, 256, 0, stream>>>(w1T, wembT, bembF, WfT, bfW);
    scan1_kernel<<<SB, 256, 0, stream>>>(counts, offs, bsums, dis, cursor);
    scan3_kernel<<<NB, 256, 0, stream>>>(offs, bsums);
    // standalone scatter: proven max-TLP shape
    scatter_kernel<<<EB, 256, 0, stream>>>(ei, offs, cursor, srcs);
    // fused-embedding gemm: h1pre = x @ Wf + bfW -> hA
    gemm_emb<<<GB, 256, 0, stream>>>(hB, (const u16*)x, flag, WfT, bfW, hA);
    // fused agg1(+b1,relu) + gemm2: hA -> hB
    fused_agg_gemm<128><<<GB, 256, 0, stream>>>(hA, offs, counts, dis, srcs, b1F, w2T, hB);
    // fused agg2(+b2,relu) + gemm3: hB -> hA (64-wide out)
    fused_agg_gemm<64><<<GB, 256, 0, stream>>>(hB, offs, counts, dis, srcs, b2F, w3T, hA);
    // fused agg3(+b3) + pool: hA -> outF
    agg_pool_kernel<<<NN / 32, 256, 0, stream>>>(hA, offs, counts, dis, srcs, b3F, batch, outF);
    // outF -> d_out
    out_cvt_kernel<<<(NG * 64 + 255) / 256, 256, 0, stream>>>(outF, d_out, flag);
}

// Round 8
// 515.021 us; speedup vs baseline: 1.1575x; 1.1575x over previous
//
#include <hip/hip_runtime.h>
#include <hip/hip_bf16.h>

#define NN 100000
#define NE 1600000
#define NG 1000
#define SMAX 48

typedef unsigned short u16;
typedef unsigned int u32;
typedef u16 u16x8 __attribute__((ext_vector_type(8)));
typedef u32 u32x4 __attribute__((ext_vector_type(4)));
typedef float f32x4 __attribute__((ext_vector_type(4)));
typedef __attribute__((ext_vector_type(8))) short s16x8;
typedef __attribute__((ext_vector_type(4))) float facc4;

__device__ __forceinline__ float bf2f(u16 u) {
    union { u32 i; float f; } c; c.i = ((u32)u) << 16; return c.f;
}
__device__ __forceinline__ u16 f2bf(float f) {
    __hip_bfloat16 h = __float2bfloat16(f);
    union { __hip_bfloat16 h; u16 u; } c; c.h = h; return c.u;
}

// ---------------- dtype detector: flag=1 if x is bf16, 0 if f32 ----------------
__global__ __launch_bounds__(256) void detect_kernel(const u32* __restrict__ xr, int* __restrict__ flag) {
    __shared__ int cnt[256];
    int c = 0;
    for (int i = threadIdx.x; i < 4096; i += 256) {
        u32 e = (xr[i] >> 7) & 0xFFu;
        if (e >= 110u && e <= 135u) c++;
    }
    cnt[threadIdx.x] = c;
    __syncthreads();
    for (int o = 128; o > 0; o >>= 1) {
        if (threadIdx.x < o) cnt[threadIdx.x] += cnt[threadIdx.x + o];
        __syncthreads();
    }
    if (threadIdx.x == 0) flag[0] = (cnt[0] > 2048) ? 1 : 0;
}

// ---------------- MEGA prep: cvt_x | cvt_wt x4 | cvt_b x4 | hist(1/thr), by block range -------
// ranges: [0,6250) cvt_x ; [6250,6474) cvt_wt ; [6474,6476) cvt_b ; [6476,12726) hist
#define MEGA_NB 12726
__global__ __launch_bounds__(256) void mega_prep(
    const void* __restrict__ x, const int* __restrict__ flag, u16* __restrict__ xb,
    const void* __restrict__ Wemb, const void* __restrict__ W1, const void* __restrict__ W2,
    const void* __restrict__ W3, u16* __restrict__ wembT, u16* __restrict__ w1T,
    u16* __restrict__ w2T, u16* __restrict__ w3T,
    const void* __restrict__ bemb, const void* __restrict__ b1, const void* __restrict__ b2,
    const void* __restrict__ b3, float* __restrict__ bembF, float* __restrict__ b1F,
    float* __restrict__ b2F, float* __restrict__ b3F,
    const int* __restrict__ ei, int* __restrict__ counts)
{
    int b = blockIdx.x, tid = threadIdx.x;
    int fl = flag[0];
    if (b < 6250) {                       // ---- cvt_x (skip when already bf16)
        if (fl) return;
        int c = b * 256 + tid;
        f32x4 a = reinterpret_cast<const f32x4*>(x)[c * 2];
        f32x4 d = reinterpret_cast<const f32x4*>(x)[c * 2 + 1];
        u16x8 o;
        #pragma unroll
        for (int j = 0; j < 4; ++j) { o[j] = f2bf(a[j]); o[4 + j] = f2bf(d[j]); }
        reinterpret_cast<u16x8*>(xb)[c] = o;
    } else if (b < 6474) {                // ---- cvt_wt (transpose W[k][m] -> Wt[m][k])
        int o = (b - 6250) * 256 + tid;
        const void* src; u16* dst; int M; int ol;
        if (o < 16384)      { src = Wemb; dst = wembT; M = 128; ol = o; }
        else if (o < 32768) { src = W1;   dst = w1T;   M = 128; ol = o - 16384; }
        else if (o < 49152) { src = W2;   dst = w2T;   M = 128; ol = o - 32768; }
        else                { src = W3;   dst = w3T;   M = 64;  ol = o - 49152; }
        int n = ol >> 7, k = ol & 127;
        u16 v = fl ? reinterpret_cast<const u16*>(src)[k * M + n]
                   : f2bf(reinterpret_cast<const float*>(src)[k * M + n]);
        dst[ol] = v;
    } else if (b < 6476) {                // ---- cvt_b
        int i = (b - 6474) * 256 + tid;
        if (i >= 448) return;
        const void* src; float* dst; int il;
        if (i < 128)      { src = bemb; dst = bembF; il = i; }
        else if (i < 256) { src = b1;   dst = b1F;   il = i - 128; }
        else if (i < 384) { src = b2;   dst = b2F;   il = i - 256; }
        else              { src = b3;   dst = b3F;   il = i - 384; }
        dst[il] = fl ? bf2f(reinterpret_cast<const u16*>(src)[il])
                     : reinterpret_cast<const float*>(src)[il];
    } else {                              // ---- hist (1 edge / thread: max TLP)
        int e = (b - 6476) * 256 + tid;
        if (e < NE) atomicAdd(&counts[ei[NE + e]], 1);
    }
}

// ---------------- wfuse: WfT = w1T @ wembT (bf16), bfW = b_emb @ W1 (f32) ----------------
__global__ __launch_bounds__(256) void wfuse_kernel(const u16* __restrict__ w1T, const u16* __restrict__ wembT,
                                                    const float* __restrict__ bembF,
                                                    u16* __restrict__ WfT, float* __restrict__ bfW) {
    int b = blockIdx.x;
    if (b < 64) {
        int o = b * 256 + threadIdx.x;    // 0..16383
        int n = o >> 7, k = o & 127;
        float acc = 0.f;
        #pragma unroll 4
        for (int j = 0; j < 128; ++j)
            acc += bf2f(w1T[n * 128 + j]) * bf2f(wembT[j * 128 + k]);
        WfT[o] = f2bf(acc);
    } else {
        int n = threadIdx.x;
        if (n < 128) {
            float acc = 0.f;
            for (int j = 0; j < 128; ++j)
                acc += bembF[j] * bf2f(w1T[n * 128 + j]);
            bfW[n] = acc;
        }
    }
}

// ---------------- scan1 (+ dis, + cursor zero) ----------------
__global__ __launch_bounds__(256) void scan1_kernel(const int* __restrict__ counts, int* __restrict__ offs,
                                                    int* __restrict__ bsums, float* __restrict__ dis,
                                                    int* __restrict__ cursor) {
    __shared__ int sums[256];
    int tid = threadIdx.x;
    int base = blockIdx.x * 2048 + tid * 8;
    int local[8];
    int s = 0;
    #pragma unroll
    for (int i = 0; i < 8; ++i) {
        int v = 0;
        if (base + i < NN) {
            v = counts[base + i];
            dis[base + i] = rsqrtf((float)v + 1.0f);
            cursor[base + i] = 0;
        }
        local[i] = s; s += v;
    }
    sums[tid] = s;
    __syncthreads();
    for (int o = 1; o < 256; o <<= 1) {
        int v = (tid >= o) ? sums[tid - o] : 0;
        __syncthreads();
        sums[tid] += v;
        __syncthreads();
    }
    int excl = sums[tid] - s;
    #pragma unroll
    for (int i = 0; i < 8; ++i)
        if (base + i < NN) offs[base + i] = excl + local[i];
    if (tid == 255) bsums[blockIdx.x] = sums[255];
}

// ---------------- scan3 (folds block-sum prefix) ----------------
__global__ __launch_bounds__(256) void scan3_kernel(int* __restrict__ offs, const int* __restrict__ bsums) {
    __shared__ int addv;
    int i = blockIdx.x * 256 + threadIdx.x;
    int bucket = blockIdx.x >> 3;
    if (threadIdx.x == 0) {
        int s = 0;
        for (int k = 0; k < bucket; ++k) s += bsums[k];
        addv = s;
    }
    __syncthreads();
    if (i < NN) offs[i] += addv;
}

// ---------------- scatter: ROUND-3 EXACT SHAPE — 1 edge/thread, int2{src, norm} --------------
// 8-byte entries measured at 78 µs vs 128-137 µs for 4-byte (fewer writers per 64B line).
__global__ __launch_bounds__(256) void scatter_kernel(const int* __restrict__ ei, const int* __restrict__ offs,
                                                      int* __restrict__ cursor, const float* __restrict__ dis,
                                                      int2* __restrict__ edges) {
    int e = blockIdx.x * 256 + threadIdx.x;
    if (e < NE) {
        int s = ei[e], d = ei[NE + e];
        int pos = offs[d] + atomicAdd(&cursor[d], 1);
        int2 pk;
        pk.x = s;
        pk.y = __float_as_int(dis[s] * dis[d]);
        edges[pos] = pk;
    }
}

// ---------------- fused-embedding GEMM: hA = x @ WfT(+LDS) + bfW ----------------
__global__ __launch_bounds__(256) void gemm_emb(const u16* __restrict__ xb, const u16* __restrict__ xraw,
                                                const int* __restrict__ flag, const u16* __restrict__ WfT,
                                                const float* __restrict__ bfW, u16* __restrict__ Hout) {
    __shared__ u16 sW[128 * 136];
    int tid = threadIdx.x;
    const u16* A = flag[0] ? xraw : xb;
    for (int c = tid; c < 128 * 16; c += 256) {
        int n = c >> 4, kc = (c & 15) << 3;
        *reinterpret_cast<u16x8*>(sW + n * 136 + kc) = reinterpret_cast<const u16x8*>(WfT)[c];
    }
    __syncthreads();
    int wv = tid >> 6, lane = tid & 63;
    int m = lane & 15, quad = lane >> 4;
    int r0 = blockIdx.x * 64 + wv * 16;
    int ar = r0 + m; if (ar >= NN) ar = NN - 1;
    facc4 acc[8];
    #pragma unroll
    for (int t = 0; t < 8; ++t) acc[t] = (facc4){0.f, 0.f, 0.f, 0.f};
    const u16* arow = A + (size_t)ar * 128 + quad * 8;
    #pragma unroll
    for (int k0 = 0; k0 < 128; k0 += 32) {
        s16x8 a = *reinterpret_cast<const s16x8*>(arow + k0);
        #pragma unroll
        for (int t = 0; t < 8; ++t) {
            s16x8 bfr = *reinterpret_cast<const s16x8*>(sW + (t * 16 + m) * 136 + k0 + quad * 8);
            acc[t] = __builtin_amdgcn_mfma_f32_16x16x32_bf16(a, bfr, acc[t], 0, 0, 0);
        }
    }
    #pragma unroll
    for (int t = 0; t < 8; ++t) {
        int col = t * 16 + m;
        float bv = bfW[col];
        #pragma unroll
        for (int r = 0; r < 4; ++r) {
            int orow = r0 + quad * 4 + r;
            if (orow < NN)
                Hout[(size_t)orow * 128 + col] = f2bf(acc[t][r] + bv);
        }
    }
}

// ---------------- FUSED: agg(128-wide, +bias, relu) -> LDS -> MFMA gemm (x W[128,MOUT]) -------
template <int MOUT>
__global__ __launch_bounds__(256) void fused_agg_gemm(const u16* __restrict__ T, const int* __restrict__ offs,
                                                      const int* __restrict__ counts, const float* __restrict__ dis,
                                                      const int2* __restrict__ edges, const float* __restrict__ aggbias,
                                                      const u16* __restrict__ Wt, u16* __restrict__ Hout) {
    constexpr int LDW = 136;
    __shared__ u16 sW[MOUT * LDW];
    __shared__ u16 sA[64 * LDW];
    int tid = threadIdx.x;
    for (int c = tid; c < MOUT * 16; c += 256) {
        int n = c >> 4, kc = (c & 15) << 3;
        *reinterpret_cast<u16x8*>(sW + n * LDW + kc) = reinterpret_cast<const u16x8*>(Wt)[c];
    }

    int lane = tid & 15, grp = tid >> 4;
    const u32x4* T4 = reinterpret_cast<const u32x4*>(T);
    for (int i = 0; i < 4; ++i) {
        int nl = grp * 4 + i;
        int n = blockIdx.x * 64 + nl;
        bool valid = n < NN;
        int nc = valid ? n : NN - 1;
        float di = dis[nc];
        float sn = di * di;
        u32x4 ts = T4[(size_t)nc * 16 + lane];
        float acc[8];
        #pragma unroll
        for (int q = 0; q < 4; ++q) {
            acc[2 * q]     = bf2f((u16)(ts[q] & 0xffffu)) * sn + aggbias[lane * 8 + 2 * q];
            acc[2 * q + 1] = bf2f((u16)(ts[q] >> 16))     * sn + aggbias[lane * 8 + 2 * q + 1];
        }
        int st = offs[nc], cnt = valid ? counts[nc] : 0;
        int j = 0;
        for (; j + 4 <= cnt; j += 4) {
            int2 e0 = edges[st + j];
            int2 e1 = edges[st + j + 1];
            int2 e2 = edges[st + j + 2];
            int2 e3 = edges[st + j + 3];
            u32x4 g0 = T4[(size_t)e0.x * 16 + lane];
            u32x4 g1 = T4[(size_t)e1.x * 16 + lane];
            u32x4 g2 = T4[(size_t)e2.x * 16 + lane];
            u32x4 g3 = T4[(size_t)e3.x * 16 + lane];
            float w0 = __int_as_float(e0.y), w1 = __int_as_float(e1.y);
            float w2 = __int_as_float(e2.y), w3 = __int_as_float(e3.y);
            #pragma unroll
            for (int q = 0; q < 4; ++q) {
                acc[2 * q]     += bf2f((u16)(g0[q] & 0xffffu)) * w0;
                acc[2 * q + 1] += bf2f((u16)(g0[q] >> 16))     * w0;
                acc[2 * q]     += bf2f((u16)(g1[q] & 0xffffu)) * w1;
                acc[2 * q + 1] += bf2f((u16)(g1[q] >> 16))     * w1;
                acc[2 * q]     += bf2f((u16)(g2[q] & 0xffffu)) * w2;
                acc[2 * q + 1] += bf2f((u16)(g2[q] >> 16))     * w2;
                acc[2 * q]     += bf2f((u16)(g3[q] & 0xffffu)) * w3;
                acc[2 * q + 1] += bf2f((u16)(g3[q] >> 16))     * w3;
            }
        }
        for (; j < cnt; ++j) {
            int2 e = edges[st + j];
            u32x4 g = T4[(size_t)e.x * 16 + lane];
            float w = __int_as_float(e.y);
            #pragma unroll
            for (int q = 0; q < 4; ++q) {
                acc[2 * q]     += bf2f((u16)(g[q] & 0xffffu)) * w;
                acc[2 * q + 1] += bf2f((u16)(g[q] >> 16))     * w;
            }
        }
        u16x8 pk;
        #pragma unroll
        for (int q = 0; q < 4; ++q) {
            pk[2 * q]     = f2bf(fmaxf(acc[2 * q], 0.0f));
            pk[2 * q + 1] = f2bf(fmaxf(acc[2 * q + 1], 0.0f));
        }
        *reinterpret_cast<u16x8*>(sA + nl * LDW + lane * 8) = pk;
    }
    __syncthreads();

    int wv = tid >> 6, l64 = tid & 63;
    int m = l64 & 15, quad = l64 >> 4;
    int r0 = blockIdx.x * 64 + wv * 16;
    constexpr int NT = MOUT / 16;
    facc4 gacc[NT];
    #pragma unroll
    for (int t = 0; t < NT; ++t) gacc[t] = (facc4){0.f, 0.f, 0.f, 0.f};
    #pragma unroll
    for (int k0 = 0; k0 < 128; k0 += 32) {
        s16x8 a = *reinterpret_cast<const s16x8*>(sA + (wv * 16 + m) * LDW + k0 + quad * 8);
        #pragma unroll
        for (int t = 0; t < NT; ++t) {
            s16x8 bfr = *reinterpret_cast<const s16x8*>(sW + (t * 16 + m) * LDW + k0 + quad * 8);
            gacc[t] = __builtin_amdgcn_mfma_f32_16x16x32_bf16(a, bfr, gacc[t], 0, 0, 0);
        }
    }
    #pragma unroll
    for (int t = 0; t < NT; ++t) {
        int col = t * 16 + m;
        #pragma unroll
        for (int r = 0; r < 4; ++r) {
            int orow = r0 + quad * 4 + r;
            if (orow < NN)
                Hout[(size_t)orow * MOUT + col] = f2bf(gacc[t][r]);
        }
    }
}

// ---------------- FUSED agg3 (+b3, no relu) + global add pool -> f32 outF ----------------
__global__ __launch_bounds__(256) void agg_pool_kernel(const u16* __restrict__ T, const int* __restrict__ offs,
                                                       const int* __restrict__ counts, const float* __restrict__ dis,
                                                       const int2* __restrict__ edges, const float* __restrict__ bias,
                                                       const int* __restrict__ batch, float* __restrict__ outF) {
    __shared__ float accG[SMAX * 64];
    __shared__ int sg0;
    int tid = threadIdx.x;
    for (int i = tid; i < SMAX * 64; i += 256) accG[i] = 0.0f;
    if (tid == 0) sg0 = batch[blockIdx.x * 32];
    __syncthreads();
    int g0 = sg0;
    int lane = tid & 7;
    int n = blockIdx.x * 32 + (tid >> 3);

    const u32x4* T4 = reinterpret_cast<const u32x4*>(T);
    float di = dis[n];
    float sn = di * di;
    u32x4 ts = T4[(size_t)n * 8 + lane];
    float acc[8];
    #pragma unroll
    for (int q = 0; q < 4; ++q) {
        acc[2 * q]     = bf2f((u16)(ts[q] & 0xffffu)) * sn + bias[lane * 8 + 2 * q];
        acc[2 * q + 1] = bf2f((u16)(ts[q] >> 16))     * sn + bias[lane * 8 + 2 * q + 1];
    }
    int st = offs[n], cnt = counts[n];
    int j = 0;
    for (; j + 4 <= cnt; j += 4) {
        int2 e0 = edges[st + j];
        int2 e1 = edges[st + j + 1];
        int2 e2 = edges[st + j + 2];
        int2 e3 = edges[st + j + 3];
        u32x4 g0v = T4[(size_t)e0.x * 8 + lane];
        u32x4 g1v = T4[(size_t)e1.x * 8 + lane];
        u32x4 g2v = T4[(size_t)e2.x * 8 + lane];
        u32x4 g3v = T4[(size_t)e3.x * 8 + lane];
        float w0 = __int_as_float(e0.y), w1 = __int_as_float(e1.y);
        float w2 = __int_as_float(e2.y), w3 = __int_as_float(e3.y);
        #pragma unroll
        for (int q = 0; q < 4; ++q) {
            acc[2 * q]     += bf2f((u16)(g0v[q] & 0xffffu)) * w0;
            acc[2 * q + 1] += bf2f((u16)(g0v[q] >> 16))     * w0;
            acc[2 * q]     += bf2f((u16)(g1v[q] & 0xffffu)) * w1;
            acc[2 * q + 1] += bf2f((u16)(g1v[q] >> 16))     * w1;
            acc[2 * q]     += bf2f((u16)(g2v[q] & 0xffffu)) * w2;
            acc[2 * q + 1] += bf2f((u16)(g2v[q] >> 16))     * w2;
            acc[2 * q]     += bf2f((u16)(g3v[q] & 0xffffu)) * w3;
            acc[2 * q + 1] += bf2f((u16)(g3v[q] >> 16))     * w3;
        }
    }
    for (; j < cnt; ++j) {
        int2 e = edges[st + j];
        u32x4 g = T4[(size_t)e.x * 8 + lane];
        float w = __int_as_float(e.y);
        #pragma unroll
        for (int q = 0; q < 4; ++q) {
            acc[2 * q]     += bf2f((u16)(g[q] & 0xffffu)) * w;
            acc[2 * q + 1] += bf2f((u16)(g[q] >> 16))     * w;
        }
    }

    int s = batch[n] - g0;
    if (s >= 0 && s < SMAX) {
        #pragma unroll
        for (int q = 0; q < 8; ++q)
            atomicAdd(&accG[s * 64 + lane * 8 + q], acc[q]);
    } else {
        #pragma unroll
        for (int q = 0; q < 8; ++q)
            atomicAdd(&outF[(size_t)(g0 + s) * 64 + lane * 8 + q], acc[q]);
    }
    __syncthreads();
    int gend = batch[blockIdx.x * 32 + 31];
    int span = gend - g0 + 1;
    if (span > SMAX) span = SMAX;
    for (int i = tid; i < span * 64; i += 256)
        atomicAdd(&outF[(size_t)g0 * 64 + i], accG[i]);
}

// ---------------- outF -> d_out (dtype branched) ----------------
__global__ __launch_bounds__(256) void out_cvt_kernel(const float* __restrict__ outF, void* __restrict__ out,
                                                      const int* __restrict__ flag) {
    int i = blockIdx.x * 256 + threadIdx.x;
    if (i < NG * 64) {
        float v = outF[i];
        if (flag[0]) reinterpret_cast<u16*>(out)[i] = f2bf(v);
        else         reinterpret_cast<float*>(out)[i] = v;
    }
}

extern "C" void kernel_launch(void* const* d_in, const int* in_sizes, int n_in,
                              void* d_out, int out_size, void* d_ws, size_t ws_size,
                              hipStream_t stream) {
    const void* x     = d_in[0];
    const int* ei     = (const int*)d_in[1];
    const int* batch  = (const int*)d_in[2];
    const void* W_emb = d_in[3];
    const void* b_emb = d_in[4];
    const void* W1    = d_in[5];
    const void* b1    = d_in[6];
    const void* W2    = d_in[7];
    const void* b2    = d_in[8];
    const void* W3    = d_in[9];
    const void* b3    = d_in[10];

    char* p = (char*)d_ws;
    auto alloc = [&](size_t bytes) { void* r = p; p += (bytes + 255) & ~(size_t)255; return r; };
    int*   flag   = (int*)alloc(256);
    int*   counts = (int*)alloc(NN * 4);
    int*   cursor = (int*)alloc(NN * 4);
    int*   offs   = (int*)alloc(NN * 4);
    float* dis    = (float*)alloc(NN * 4);
    int*   bsums  = (int*)alloc(256 * 4);
    int2*  edges  = (int2*)alloc((size_t)NE * 8);
    u16*   wembT  = (u16*)alloc(128 * 128 * 2);
    u16*   w1T    = (u16*)alloc(128 * 128 * 2);
    u16*   w2T    = (u16*)alloc(128 * 128 * 2);
    u16*   w3T    = (u16*)alloc(64 * 128 * 2);
    u16*   WfT    = (u16*)alloc(128 * 128 * 2);
    float* bembF  = (float*)alloc(128 * 4);
    float* b1F    = (float*)alloc(128 * 4);
    float* b2F    = (float*)alloc(128 * 4);
    float* b3F    = (float*)alloc(64 * 4);
    float* bfW    = (float*)alloc(128 * 4);
    float* outF   = (float*)alloc((size_t)NG * 64 * 4);
    u16*   hA     = (u16*)alloc((size_t)(NN + 64) * 128 * 2);
    u16*   hB     = (u16*)alloc((size_t)(NN + 64) * 128 * 2);   // holds canonical bf16 x first

    hipMemsetAsync(counts, 0, NN * 4, stream);
    hipMemsetAsync(outF, 0, (size_t)NG * 64 * 4, stream);

    const int SB = (NN + 2047) / 2048;   // 49
    const int NB = (NN + 255) / 256;     // 391
    const int GB = (NN + 63) / 64;       // 1563
    const int EB = (NE + 255) / 256;     // 6250

    detect_kernel<<<1, 256, 0, stream>>>((const u32*)x, flag);
    mega_prep<<<MEGA_NB, 256, 0, stream>>>(x, flag, hB, W_emb, W1, W2, W3, wembT, w1T, w2T, w3T,
                                           b_emb, b1, b2, b3, bembF, b1F, b2F, b3F, ei, counts);
    // Wf = W_emb @ W1 (folds layer-1 transform into the embedding GEMM)
    wfuse_kernel<<<65, 256, 0, stream>>>(w1T, wembT, bembF, WfT, bfW);
    scan1_kernel<<<SB, 256, 0, stream>>>(counts, offs, bsums, dis, cursor);
    scan3_kernel<<<NB, 256, 0, stream>>>(offs, bsums);
    // standalone scatter, round-3 proven int2 shape
    scatter_kernel<<<EB, 256, 0, stream>>>(ei, offs, cursor, dis, edges);
    // fused-embedding gemm: h1pre = x @ Wf + bfW -> hA
    gemm_emb<<<GB, 256, 0, stream>>>(hB, (const u16*)x, flag, WfT, bfW, hA);
    // fused agg1(+b1,relu) + gemm2: hA -> hB
    fused_agg_gemm<128><<<GB, 256, 0, stream>>>(hA, offs, counts, dis, edges, b1F, w2T, hB);
    // fused agg2(+b2,relu) + gemm3: hB -> hA (64-wide out)
    fused_agg_gemm<64><<<GB, 256, 0, stream>>>(hB, offs, counts, dis, edges, b2F, w3T, hA);
    // fused agg3(+b3) + pool: hA -> outF
    agg_pool_kernel<<<NN / 32, 256, 0, stream>>>(hA, offs, counts, dis, edges, b3F, batch, outF);
    // outF -> d_out
    out_cvt_kernel<<<(NG * 64 + 255) / 256, 256, 0, stream>>>(outF, d_out, flag);
}

// Round 9
// 482.140 us; speedup vs baseline: 1.2364x; 1.0682x over previous
//
#include <hip/hip_runtime.h>
#include <hip/hip_bf16.h>

#define NN 100000
#define NE 1600000
#define NG 1000
#define SMAX 48

typedef unsigned short u16;
typedef unsigned int u32;
typedef u16 u16x8 __attribute__((ext_vector_type(8)));
typedef u32 u32x4 __attribute__((ext_vector_type(4)));
typedef float f32x4 __attribute__((ext_vector_type(4)));
typedef __attribute__((ext_vector_type(8))) short s16x8;
typedef __attribute__((ext_vector_type(4))) float facc4;

__device__ __forceinline__ float bf2f(u16 u) {
    union { u32 i; float f; } c; c.i = ((u32)u) << 16; return c.f;
}
__device__ __forceinline__ u16 f2bf(float f) {
    __hip_bfloat16 h = __float2bfloat16(f);
    union { __hip_bfloat16 h; u16 u; } c; c.h = h; return c.u;
}

// ---------------- dtype detector: flag=1 if x is bf16, 0 if f32 ----------------
__global__ __launch_bounds__(256) void detect_kernel(const u32* __restrict__ xr, int* __restrict__ flag) {
    __shared__ int cnt[256];
    int c = 0;
    for (int i = threadIdx.x; i < 4096; i += 256) {
        u32 e = (xr[i] >> 7) & 0xFFu;
        if (e >= 110u && e <= 135u) c++;
    }
    cnt[threadIdx.x] = c;
    __syncthreads();
    for (int o = 128; o > 0; o >>= 1) {
        if (threadIdx.x < o) cnt[threadIdx.x] += cnt[threadIdx.x + o];
        __syncthreads();
    }
    if (threadIdx.x == 0) flag[0] = (cnt[0] > 2048) ? 1 : 0;
}

// ---------------- MEGA prep: cvt_x | cvt_wt x4 | cvt_b x4 | hist+rank, by block range ---------
// ranges: [0,6250) cvt_x ; [6250,6474) cvt_wt ; [6474,6476) cvt_b ; [6476,12726) hist
#define MEGA_NB 12726
__global__ __launch_bounds__(256) void mega_prep(
    const void* __restrict__ x, const int* __restrict__ flag, u16* __restrict__ xb,
    const void* __restrict__ Wemb, const void* __restrict__ W1, const void* __restrict__ W2,
    const void* __restrict__ W3, u16* __restrict__ wembT, u16* __restrict__ w1T,
    u16* __restrict__ w2T, u16* __restrict__ w3T,
    const void* __restrict__ bemb, const void* __restrict__ b1, const void* __restrict__ b2,
    const void* __restrict__ b3, float* __restrict__ bembF, float* __restrict__ b1F,
    float* __restrict__ b2F, float* __restrict__ b3F,
    const int* __restrict__ ei, int* __restrict__ counts, int* __restrict__ erank)
{
    int b = blockIdx.x, tid = threadIdx.x;
    int fl = flag[0];
    if (b < 6250) {                       // ---- cvt_x (skip when already bf16)
        if (fl) return;
        int c = b * 256 + tid;
        f32x4 a = reinterpret_cast<const f32x4*>(x)[c * 2];
        f32x4 d = reinterpret_cast<const f32x4*>(x)[c * 2 + 1];
        u16x8 o;
        #pragma unroll
        for (int j = 0; j < 4; ++j) { o[j] = f2bf(a[j]); o[4 + j] = f2bf(d[j]); }
        reinterpret_cast<u16x8*>(xb)[c] = o;
    } else if (b < 6474) {                // ---- cvt_wt (transpose W[k][m] -> Wt[m][k])
        int o = (b - 6250) * 256 + tid;
        const void* src; u16* dst; int M; int ol;
        if (o < 16384)      { src = Wemb; dst = wembT; M = 128; ol = o; }
        else if (o < 32768) { src = W1;   dst = w1T;   M = 128; ol = o - 16384; }
        else if (o < 49152) { src = W2;   dst = w2T;   M = 128; ol = o - 32768; }
        else                { src = W3;   dst = w3T;   M = 64;  ol = o - 49152; }
        int n = ol >> 7, k = ol & 127;
        u16 v = fl ? reinterpret_cast<const u16*>(src)[k * M + n]
                   : f2bf(reinterpret_cast<const float*>(src)[k * M + n]);
        dst[ol] = v;
    } else if (b < 6476) {                // ---- cvt_b
        int i = (b - 6474) * 256 + tid;
        if (i >= 448) return;
        const void* src; float* dst; int il;
        if (i < 128)      { src = bemb; dst = bembF; il = i; }
        else if (i < 256) { src = b1;   dst = b1F;   il = i - 128; }
        else if (i < 384) { src = b2;   dst = b2F;   il = i - 256; }
        else              { src = b3;   dst = b3F;   il = i - 384; }
        dst[il] = fl ? bf2f(reinterpret_cast<const u16*>(src)[il])
                     : reinterpret_cast<const float*>(src)[il];
    } else {                              // ---- hist: atomicAdd returns the edge's rank — keep it
        int e = (b - 6476) * 256 + tid;
        if (e < NE) {
            int d = ei[NE + e];
            erank[e] = atomicAdd(&counts[d], 1);
        }
    }
}

// ---------------- wfuse: WfT = w1T @ wembT (bf16), bfW = b_emb @ W1 (f32) ----------------
__global__ __launch_bounds__(256) void wfuse_kernel(const u16* __restrict__ w1T, const u16* __restrict__ wembT,
                                                    const float* __restrict__ bembF,
                                                    u16* __restrict__ WfT, float* __restrict__ bfW) {
    int b = blockIdx.x;
    if (b < 64) {
        int o = b * 256 + threadIdx.x;    // 0..16383
        int n = o >> 7, k = o & 127;
        float acc = 0.f;
        #pragma unroll 4
        for (int j = 0; j < 128; ++j)
            acc += bf2f(w1T[n * 128 + j]) * bf2f(wembT[j * 128 + k]);
        WfT[o] = f2bf(acc);
    } else {
        int n = threadIdx.x;
        if (n < 128) {
            float acc = 0.f;
            for (int j = 0; j < 128; ++j)
                acc += bembF[j] * bf2f(w1T[n * 128 + j]);
            bfW[n] = acc;
        }
    }
}

// ---------------- scan1 (+ dis) ----------------
__global__ __launch_bounds__(256) void scan1_kernel(const int* __restrict__ counts, int* __restrict__ offs,
                                                    int* __restrict__ bsums, float* __restrict__ dis) {
    __shared__ int sums[256];
    int tid = threadIdx.x;
    int base = blockIdx.x * 2048 + tid * 8;
    int local[8];
    int s = 0;
    #pragma unroll
    for (int i = 0; i < 8; ++i) {
        int v = 0;
        if (base + i < NN) {
            v = counts[base + i];
            dis[base + i] = rsqrtf((float)v + 1.0f);
        }
        local[i] = s; s += v;
    }
    sums[tid] = s;
    __syncthreads();
    for (int o = 1; o < 256; o <<= 1) {
        int v = (tid >= o) ? sums[tid - o] : 0;
        __syncthreads();
        sums[tid] += v;
        __syncthreads();
    }
    int excl = sums[tid] - s;
    #pragma unroll
    for (int i = 0; i < 8; ++i)
        if (base + i < NN) offs[base + i] = excl + local[i];
    if (tid == 255) bsums[blockIdx.x] = sums[255];
}

// ---------------- scan3 (folds block-sum prefix) ----------------
__global__ __launch_bounds__(256) void scan3_kernel(int* __restrict__ offs, const int* __restrict__ bsums) {
    __shared__ int addv;
    int i = blockIdx.x * 256 + threadIdx.x;
    int bucket = blockIdx.x >> 3;
    if (threadIdx.x == 0) {
        int s = 0;
        for (int k = 0; k < bucket; ++k) s += bsums[k];
        addv = s;
    }
    __syncthreads();
    if (i < NN) offs[i] += addv;
}

// ---------------- scatter: atomic-free (rank precomputed), 1 edge/thread, int2 entries --------
__global__ __launch_bounds__(256) void scatter_kernel(const int* __restrict__ ei, const int* __restrict__ offs,
                                                      const int* __restrict__ erank, const float* __restrict__ dis,
                                                      int2* __restrict__ edges) {
    int e = blockIdx.x * 256 + threadIdx.x;
    if (e < NE) {
        int s = ei[e], d = ei[NE + e];
        int pos = offs[d] + erank[e];
        int2 pk;
        pk.x = s;
        pk.y = __float_as_int(dis[s] * dis[d]);
        edges[pos] = pk;
    }
}

// ---------------- fused-embedding GEMM: hA = x @ WfT(+LDS) + bfW ----------------
__global__ __launch_bounds__(256) void gemm_emb(const u16* __restrict__ xb, const u16* __restrict__ xraw,
                                                const int* __restrict__ flag, const u16* __restrict__ WfT,
                                                const float* __restrict__ bfW, u16* __restrict__ Hout) {
    __shared__ u16 sW[128 * 136];
    int tid = threadIdx.x;
    const u16* A = flag[0] ? xraw : xb;
    for (int c = tid; c < 128 * 16; c += 256) {
        int n = c >> 4, kc = (c & 15) << 3;
        *reinterpret_cast<u16x8*>(sW + n * 136 + kc) = reinterpret_cast<const u16x8*>(WfT)[c];
    }
    __syncthreads();
    int wv = tid >> 6, lane = tid & 63;
    int m = lane & 15, quad = lane >> 4;
    int r0 = blockIdx.x * 64 + wv * 16;
    int ar = r0 + m; if (ar >= NN) ar = NN - 1;
    facc4 acc[8];
    #pragma unroll
    for (int t = 0; t < 8; ++t) acc[t] = (facc4){0.f, 0.f, 0.f, 0.f};
    const u16* arow = A + (size_t)ar * 128 + quad * 8;
    #pragma unroll
    for (int k0 = 0; k0 < 128; k0 += 32) {
        s16x8 a = *reinterpret_cast<const s16x8*>(arow + k0);
        #pragma unroll
        for (int t = 0; t < 8; ++t) {
            s16x8 bfr = *reinterpret_cast<const s16x8*>(sW + (t * 16 + m) * 136 + k0 + quad * 8);
            acc[t] = __builtin_amdgcn_mfma_f32_16x16x32_bf16(a, bfr, acc[t], 0, 0, 0);
        }
    }
    #pragma unroll
    for (int t = 0; t < 8; ++t) {
        int col = t * 16 + m;
        float bv = bfW[col];
        #pragma unroll
        for (int r = 0; r < 4; ++r) {
            int orow = r0 + quad * 4 + r;
            if (orow < NN)
                Hout[(size_t)orow * 128 + col] = f2bf(acc[t][r] + bv);
        }
    }
}

// ---------------- FUSED: agg(128-wide,+bias,relu) -> REGISTERS -> MFMA gemm (x W[128,MOUT]) ----
// No sA staging: thread (wv, m=lane&15, quad) aggregates exactly the 32 features
// {32c + quad*8 + j} of node wv*16+m that its MFMA A-fragment needs.
template <int MOUT>
__global__ __launch_bounds__(256) void fused_agg_gemm(const u16* __restrict__ T, const int* __restrict__ offs,
                                                      const int* __restrict__ counts, const float* __restrict__ dis,
                                                      const int2* __restrict__ edges, const float* __restrict__ aggbias,
                                                      const u16* __restrict__ Wt, u16* __restrict__ Hout) {
    constexpr int LDW = 136;
    __shared__ u16 sW[MOUT * LDW];
    int tid = threadIdx.x;
    for (int c = tid; c < MOUT * 16; c += 256) {
        int n = c >> 4, kc = (c & 15) << 3;
        *reinterpret_cast<u16x8*>(sW + n * LDW + kc) = reinterpret_cast<const u16x8*>(Wt)[c];
    }

    int wv = tid >> 6, lane = tid & 63;
    int m = lane & 15, quad = lane >> 4;
    int n = blockIdx.x * 64 + wv * 16 + m;
    bool valid = n < NN;
    int nc = valid ? n : NN - 1;
    const u32x4* T4 = reinterpret_cast<const u32x4*>(T);

    float di = dis[nc];
    float sn = di * di;
    float acc[4][8];
    #pragma unroll
    for (int c = 0; c < 4; ++c) {
        u32x4 ts = T4[(size_t)nc * 16 + quad + 4 * c];
        #pragma unroll
        for (int q = 0; q < 4; ++q) {
            int f = c * 32 + quad * 8 + 2 * q;
            acc[c][2 * q]     = bf2f((u16)(ts[q] & 0xffffu)) * sn + aggbias[f];
            acc[c][2 * q + 1] = bf2f((u16)(ts[q] >> 16))     * sn + aggbias[f + 1];
        }
    }
    int st = offs[nc], cnt = valid ? counts[nc] : 0;
    int j = 0;
    for (; j + 2 <= cnt; j += 2) {       // 2 edges x 4 chunks = 8 gathers in flight
        int2 e0 = edges[st + j];
        int2 e1 = edges[st + j + 1];
        u32x4 g0[4], g1[4];
        #pragma unroll
        for (int c = 0; c < 4; ++c) g0[c] = T4[(size_t)e0.x * 16 + quad + 4 * c];
        #pragma unroll
        for (int c = 0; c < 4; ++c) g1[c] = T4[(size_t)e1.x * 16 + quad + 4 * c];
        float w0 = __int_as_float(e0.y), w1 = __int_as_float(e1.y);
        #pragma unroll
        for (int c = 0; c < 4; ++c)
            #pragma unroll
            for (int q = 0; q < 4; ++q) {
                acc[c][2 * q]     += bf2f((u16)(g0[c][q] & 0xffffu)) * w0;
                acc[c][2 * q + 1] += bf2f((u16)(g0[c][q] >> 16))     * w0;
                acc[c][2 * q]     += bf2f((u16)(g1[c][q] & 0xffffu)) * w1;
                acc[c][2 * q + 1] += bf2f((u16)(g1[c][q] >> 16))     * w1;
            }
    }
    for (; j < cnt; ++j) {
        int2 e = edges[st + j];
        u32x4 g[4];
        #pragma unroll
        for (int c = 0; c < 4; ++c) g[c] = T4[(size_t)e.x * 16 + quad + 4 * c];
        float w = __int_as_float(e.y);
        #pragma unroll
        for (int c = 0; c < 4; ++c)
            #pragma unroll
            for (int q = 0; q < 4; ++q) {
                acc[c][2 * q]     += bf2f((u16)(g[c][q] & 0xffffu)) * w;
                acc[c][2 * q + 1] += bf2f((u16)(g[c][q] >> 16))     * w;
            }
    }

    // relu + pack directly into A-fragments (registers)
    s16x8 afrag[4];
    #pragma unroll
    for (int c = 0; c < 4; ++c)
        #pragma unroll
        for (int i = 0; i < 8; ++i)
            afrag[c][i] = (short)f2bf(fmaxf(acc[c][i], 0.0f));

    __syncthreads();   // sW staging visible to all

    constexpr int NT = MOUT / 16;
    facc4 gacc[NT];
    #pragma unroll
    for (int t = 0; t < NT; ++t) gacc[t] = (facc4){0.f, 0.f, 0.f, 0.f};
    #pragma unroll
    for (int c = 0; c < 4; ++c) {        // k0 = 32*c
        #pragma unroll
        for (int t = 0; t < NT; ++t) {
            s16x8 bfr = *reinterpret_cast<const s16x8*>(sW + (t * 16 + m) * LDW + 32 * c + quad * 8);
            gacc[t] = __builtin_amdgcn_mfma_f32_16x16x32_bf16(afrag[c], bfr, gacc[t], 0, 0, 0);
        }
    }
    int r0 = blockIdx.x * 64 + wv * 16;
    #pragma unroll
    for (int t = 0; t < NT; ++t) {
        int col = t * 16 + m;
        #pragma unroll
        for (int r = 0; r < 4; ++r) {
            int orow = r0 + quad * 4 + r;
            if (orow < NN)
                Hout[(size_t)orow * MOUT + col] = f2bf(gacc[t][r]);
        }
    }
}

// ---------------- FUSED agg3 (+b3, no relu) + global add pool -> f32 outF ----------------
__global__ __launch_bounds__(256) void agg_pool_kernel(const u16* __restrict__ T, const int* __restrict__ offs,
                                                       const int* __restrict__ counts, const float* __restrict__ dis,
                                                       const int2* __restrict__ edges, const float* __restrict__ bias,
                                                       const int* __restrict__ batch, float* __restrict__ outF) {
    __shared__ float accG[SMAX * 64];
    __shared__ int sg0;
    int tid = threadIdx.x;
    for (int i = tid; i < SMAX * 64; i += 256) accG[i] = 0.0f;
    if (tid == 0) sg0 = batch[blockIdx.x * 32];
    __syncthreads();
    int g0 = sg0;
    int lane = tid & 7;
    int n = blockIdx.x * 32 + (tid >> 3);

    const u32x4* T4 = reinterpret_cast<const u32x4*>(T);
    float di = dis[n];
    float sn = di * di;
    u32x4 ts = T4[(size_t)n * 8 + lane];
    float acc[8];
    #pragma unroll
    for (int q = 0; q < 4; ++q) {
        acc[2 * q]     = bf2f((u16)(ts[q] & 0xffffu)) * sn + bias[lane * 8 + 2 * q];
        acc[2 * q + 1] = bf2f((u16)(ts[q] >> 16))     * sn + bias[lane * 8 + 2 * q + 1];
    }
    int st = offs[n], cnt = counts[n];
    int j = 0;
    for (; j + 4 <= cnt; j += 4) {
        int2 e0 = edges[st + j];
        int2 e1 = edges[st + j + 1];
        int2 e2 = edges[st + j + 2];
        int2 e3 = edges[st + j + 3];
        u32x4 g0v = T4[(size_t)e0.x * 8 + lane];
        u32x4 g1v = T4[(size_t)e1.x * 8 + lane];
        u32x4 g2v = T4[(size_t)e2.x * 8 + lane];
        u32x4 g3v = T4[(size_t)e3.x * 8 + lane];
        float w0 = __int_as_float(e0.y), w1 = __int_as_float(e1.y);
        float w2 = __int_as_float(e2.y), w3 = __int_as_float(e3.y);
        #pragma unroll
        for (int q = 0; q < 4; ++q) {
            acc[2 * q]     += bf2f((u16)(g0v[q] & 0xffffu)) * w0;
            acc[2 * q + 1] += bf2f((u16)(g0v[q] >> 16))     * w0;
            acc[2 * q]     += bf2f((u16)(g1v[q] & 0xffffu)) * w1;
            acc[2 * q + 1] += bf2f((u16)(g1v[q] >> 16))     * w1;
            acc[2 * q]     += bf2f((u16)(g2v[q] & 0xffffu)) * w2;
            acc[2 * q + 1] += bf2f((u16)(g2v[q] >> 16))     * w2;
            acc[2 * q]     += bf2f((u16)(g3v[q] & 0xffffu)) * w3;
            acc[2 * q + 1] += bf2f((u16)(g3v[q] >> 16))     * w3;
        }
    }
    for (; j < cnt; ++j) {
        int2 e = edges[st + j];
        u32x4 g = T4[(size_t)e.x * 8 + lane];
        float w = __int_as_float(e.y);
        #pragma unroll
        for (int q = 0; q < 4; ++q) {
            acc[2 * q]     += bf2f((u16)(g[q] & 0xffffu)) * w;
            acc[2 * q + 1] += bf2f((u16)(g[q] >> 16))     * w;
        }
    }

    int s = batch[n] - g0;
    if (s >= 0 && s < SMAX) {
        #pragma unroll
        for (int q = 0; q < 8; ++q)
            atomicAdd(&accG[s * 64 + lane * 8 + q], acc[q]);
    } else {
        #pragma unroll
        for (int q = 0; q < 8; ++q)
            atomicAdd(&outF[(size_t)(g0 + s) * 64 + lane * 8 + q], acc[q]);
    }
    __syncthreads();
    int gend = batch[blockIdx.x * 32 + 31];
    int span = gend - g0 + 1;
    if (span > SMAX) span = SMAX;
    for (int i = tid; i < span * 64; i += 256)
        atomicAdd(&outF[(size_t)g0 * 64 + i], accG[i]);
}

// ---------------- outF -> d_out (dtype branched) ----------------
__global__ __launch_bounds__(256) void out_cvt_kernel(const float* __restrict__ outF, void* __restrict__ out,
                                                      const int* __restrict__ flag) {
    int i = blockIdx.x * 256 + threadIdx.x;
    if (i < NG * 64) {
        float v = outF[i];
        if (flag[0]) reinterpret_cast<u16*>(out)[i] = f2bf(v);
        else         reinterpret_cast<float*>(out)[i] = v;
    }
}

extern "C" void kernel_launch(void* const* d_in, const int* in_sizes, int n_in,
                              void* d_out, int out_size, void* d_ws, size_t ws_size,
                              hipStream_t stream) {
    const void* x     = d_in[0];
    const int* ei     = (const int*)d_in[1];
    const int* batch  = (const int*)d_in[2];
    const void* W_emb = d_in[3];
    const void* b_emb = d_in[4];
    const void* W1    = d_in[5];
    const void* b1    = d_in[6];
    const void* W2    = d_in[7];
    const void* b2    = d_in[8];
    const void* W3    = d_in[9];
    const void* b3    = d_in[10];

    char* p = (char*)d_ws;
    auto alloc = [&](size_t bytes) { void* r = p; p += (bytes + 255) & ~(size_t)255; return r; };
    int*   flag   = (int*)alloc(256);
    int*   counts = (int*)alloc(NN * 4);
    int*   offs   = (int*)alloc(NN * 4);
    float* dis    = (float*)alloc(NN * 4);
    int*   bsums  = (int*)alloc(256 * 4);
    int2*  edges  = (int2*)alloc((size_t)NE * 8);
    u16*   wembT  = (u16*)alloc(128 * 128 * 2);
    u16*   w1T    = (u16*)alloc(128 * 128 * 2);
    u16*   w2T    = (u16*)alloc(128 * 128 * 2);
    u16*   w3T    = (u16*)alloc(64 * 128 * 2);
    u16*   WfT    = (u16*)alloc(128 * 128 * 2);
    float* bembF  = (float*)alloc(128 * 4);
    float* b1F    = (float*)alloc(128 * 4);
    float* b2F    = (float*)alloc(128 * 4);
    float* b3F    = (float*)alloc(64 * 4);
    float* bfW    = (float*)alloc(128 * 4);
    float* outF   = (float*)alloc((size_t)NG * 64 * 4);
    u16*   hA     = (u16*)alloc((size_t)(NN + 64) * 128 * 2);
    u16*   hB     = (u16*)alloc((size_t)(NN + 64) * 128 * 2);   // holds canonical bf16 x first
    // erank aliases hA: consumed by scatter BEFORE gemm_emb writes hA (sequential stream order)
    int*   erank  = (int*)hA;

    hipMemsetAsync(counts, 0, NN * 4, stream);
    hipMemsetAsync(outF, 0, (size_t)NG * 64 * 4, stream);

    const int SB = (NN + 2047) / 2048;   // 49
    const int NB = (NN + 255) / 256;     // 391
    const int GB = (NN + 63) / 64;       // 1563
    const int EB = (NE + 255) / 256;     // 6250

    detect_kernel<<<1, 256, 0, stream>>>((const u32*)x, flag);
    mega_prep<<<MEGA_NB, 256, 0, stream>>>(x, flag, hB, W_emb, W1, W2, W3, wembT, w1T, w2T, w3T,
                                           b_emb, b1, b2, b3, bembF, b1F, b2F, b3F, ei, counts, erank);
    // Wf = W_emb @ W1 (folds layer-1 transform into the embedding GEMM)
    wfuse_kernel<<<65, 256, 0, stream>>>(w1T, wembT, bembF, WfT, bfW);
    scan1_kernel<<<SB, 256, 0, stream>>>(counts, offs, bsums, dis);
    scan3_kernel<<<NB, 256, 0, stream>>>(offs, bsums);
    // atomic-free scatter (rank precomputed in mega_prep)
    scatter_kernel<<<EB, 256, 0, stream>>>(ei, offs, erank, dis, edges);
    // fused-embedding gemm: h1pre = x @ Wf + bfW -> hA  (overwrites erank region, now dead)
    gemm_emb<<<GB, 256, 0, stream>>>(hB, (const u16*)x, flag, WfT, bfW, hA);
    // fused agg1(+b1,relu) + gemm2: hA -> hB
    fused_agg_gemm<128><<<GB, 256, 0, stream>>>(hA, offs, counts, dis, edges, b1F, w2T, hB);
    // fused agg2(+b2,relu) + gemm3: hB -> hA (64-wide out)
    fused_agg_gemm<64><<<GB, 256, 0, stream>>>(hB, offs, counts, dis, edges, b2F, w3T, hA);
    // fused agg3(+b3) + pool: hA -> outF
    agg_pool_kernel<<<NN / 32, 256, 0, stream>>>(hA, offs, counts, dis, edges, b3F, batch, outF);
    // outF -> d_out
    out_cvt_kernel<<<(NG * 64 + 255) / 256, 256, 0, stream>>>(outF, d_out, flag);
}